// Round 16
// baseline (150.856 us; speedup 1.0000x reference)
//
#include <hip/hip_runtime.h>
#include <math.h>

// B=16,H=14,W=14,D=512, L=32, HID=512, A=512. fp32 in/out, all-fp32 compute.
// R16: ONE kernel, 256 independent blocks (b, l-pair), ZERO inter-block sync,
// ZERO workspace. Key: hlin row (b,l) and ctx row (b,l) are each consumed by
// exactly one block -> computing them in-block is the same total FLOPs. Only
// cost: W_hidden/W_co re-read per block (512 MB L2/L3 aggregate ~ 15 us).
// Five sync designs (R8-R15) all cost ~45-50 us regardless of mechanism; the
// fix is needing none.

__global__ __launch_bounds__(256) void coatt_onekernel(
    const float* __restrict__ maps, const float* __restrict__ hiddens,
    const float* __restrict__ W_hidden, const float* __restrict__ b_hidden,
    const float* __restrict__ W_rect, const float* __restrict__ b_rect,
    const float* __restrict__ W_co, const float* __restrict__ b_co,
    float* __restrict__ out_co, float* __restrict__ out_attn)
{
    __shared__ float hid0[512], hid1[512], wv[512];   // hiddens rows, W_rect
    __shared__ float hl0[512], hl1[512];              // hlin rows
    __shared__ float ctx0[512], ctx1[512];            // ctx rows
    __shared__ float ftile[16 * 516];                 // maps chunk (33 KB)
    __shared__ float sraw[2 * 208];                   // raw scores
    __shared__ float ep[32];                          // chunk exp weights
    __shared__ float bc[4];                           // chunk max/sum

    const int b = blockIdx.x >> 4, s = blockIdx.x & 15;
    const int l0 = 2 * s;
    const int tid = threadIdx.x;
    const int kc = tid & 15, aslot = tid >> 4;        // 16 k-chunks x 16 a-slots

    // stage hiddens rows l0,l0+1 and W_rect
    {
        const float4* H0 = (const float4*)(hiddens + ((size_t)b * 32 + l0) * 512);
        const float4* H1 = (const float4*)(hiddens + ((size_t)b * 32 + l0 + 1) * 512);
        const float4* WV = (const float4*)W_rect;
        if (tid < 128) { ((float4*)hid0)[tid] = H0[tid]; ((float4*)wv)[tid] = WV[tid]; }
        else           { ((float4*)hid1)[tid - 128] = H1[tid - 128]; }
    }
    __syncthreads();

    // rotated k-offsets within this thread's 32-float k-slice (bank-friendly)
    int koff[8];
    #pragma unroll
    for (int j = 0; j < 8; ++j) koff[j] = kc * 32 + ((j + kc) & 7) * 4;

    // ---- Phase 1: hlin rows l0,l0+1 = hiddens_row . W_hidden^T + b_hidden ----
    {
        float4 hA[8], hB[8];
        #pragma unroll
        for (int j = 0; j < 8; ++j) {
            hA[j] = *(const float4*)&hid0[koff[j]];
            hB[j] = *(const float4*)&hid1[koff[j]];
        }
        for (int it = 0; it < 32; ++it) {
            const int a = it * 16 + aslot;
            const float* wrow = W_hidden + (size_t)a * 512;
            float a0 = 0.f, a1 = 0.f;
            #pragma unroll
            for (int j = 0; j < 8; ++j) {
                const float4 w = *(const float4*)(wrow + koff[j]);
                a0 += w.x*hA[j].x + w.y*hA[j].y + w.z*hA[j].z + w.w*hA[j].w;
                a1 += w.x*hB[j].x + w.y*hB[j].y + w.z*hB[j].z + w.w*hB[j].w;
            }
            #pragma unroll
            for (int msk = 1; msk <= 8; msk <<= 1) {
                a0 += __shfl_xor(a0, msk);
                a1 += __shfl_xor(a1, msk);
            }
            if (kc == 0) {
                const float bh = b_hidden[a];
                hl0[a] = a0 + bh;
                hl1[a] = a1 + bh;
            }
        }
    }
    __syncthreads();

    // ---- Phase 2: scores + online softmax + ctx (maps read once) ----
    {
        const int pi = tid >> 4, k = kc;
        int aoff[8];
        float4 h0r[8], h1r[8], wr[8];
        #pragma unroll
        for (int j = 0; j < 8; ++j) {
            aoff[j] = koff[j];                        // same rotation
            h0r[j] = *(const float4*)&hl0[aoff[j]];
            h1r[j] = *(const float4*)&hl1[aoff[j]];
            wr[j]  = *(const float4*)&wv[aoff[j]];
        }
        const float* mb = maps + (size_t)b * 196 * 512;
        const float br = b_rect[0];
        const int d0 = tid * 2;

        float m0 = -INFINITY, m1 = -INFINITY, ls0 = 0.f, ls1 = 0.f;
        float cA0 = 0.f, cA1 = 0.f, cB0 = 0.f, cB1 = 0.f;

        for (int c = 0; c < 13; ++c) {
            __syncthreads();                          // ftile reuse safety
            #pragma unroll
            for (int it = 0; it < 8; ++it) {
                const int idx = tid + 256 * it;       // 0..2047 float4
                const int r = idx >> 7, c4 = idx & 127;
                int p = c * 16 + r; if (p > 195) p = 195;
                *(float4*)&ftile[r * 516 + c4 * 4] =
                    *(const float4*)(mb + (size_t)p * 512 + c4 * 4);
            }
            __syncthreads();

            float s0 = 0.f, s1 = 0.f;
            #pragma unroll
            for (int j = 0; j < 8; ++j) {
                const float4 f = *(const float4*)&ftile[pi * 516 + aoff[j]];
                const float4 A = h0r[j], Bv = h1r[j], W = wr[j];
                s0 += fmaxf(f.x + A.x, 0.f) * W.x + fmaxf(f.y + A.y, 0.f) * W.y
                    + fmaxf(f.z + A.z, 0.f) * W.z + fmaxf(f.w + A.w, 0.f) * W.w;
                s1 += fmaxf(f.x + Bv.x, 0.f) * W.x + fmaxf(f.y + Bv.y, 0.f) * W.y
                    + fmaxf(f.z + Bv.z, 0.f) * W.z + fmaxf(f.w + Bv.w, 0.f) * W.w;
            }
            #pragma unroll
            for (int msk = 1; msk <= 8; msk <<= 1) {
                s0 += __shfl_xor(s0, msk);
                s1 += __shfl_xor(s1, msk);
            }
            if (k == 0) {
                const int p = c * 16 + pi;
                const bool ok = (p <= 195);
                sraw[p]       = ok ? (s0 + br) : -INFINITY;
                sraw[208 + p] = ok ? (s1 + br) : -INFINITY;
            }
            __syncthreads();

            if (tid < 32) {                           // l = tid>>4, pl = tid&15
                const int l = tid >> 4, pl = tid & 15;
                const float sc = sraw[l * 208 + c * 16 + pl];
                float mx = sc;
                #pragma unroll
                for (int msk = 1; msk <= 8; msk <<= 1) mx = fmaxf(mx, __shfl_xor(mx, msk));
                const float nm = fmaxf(l ? m1 : m0, mx);
                const float e = (sc == -INFINITY) ? 0.f : __expf(sc - nm);
                ep[l * 16 + pl] = e;
                float es = e;
                #pragma unroll
                for (int msk = 1; msk <= 8; msk <<= 1) es += __shfl_xor(es, msk);
                if (pl == 0) { bc[l] = mx; bc[2 + l] = es; }
            }
            __syncthreads();

            const float nm0 = fmaxf(m0, bc[0]), nm1 = fmaxf(m1, bc[1]);
            const float al0 = __expf(m0 - nm0), al1 = __expf(m1 - nm1);
            ls0 = ls0 * al0 + bc[2];
            ls1 = ls1 * al1 + bc[3];
            m0 = nm0; m1 = nm1;
            cA0 *= al0; cA1 *= al0; cB0 *= al1; cB1 *= al1;
            #pragma unroll
            for (int r = 0; r < 16; ++r) {
                const float2 f = *(const float2*)&ftile[r * 516 + d0];
                const float w0 = ep[r], w1 = ep[16 + r];
                cA0 += w0 * f.x; cA1 += w0 * f.y;
                cB0 += w1 * f.x; cB1 += w1 * f.y;
            }
        }

        const float inv0 = 1.f / ls0, inv1 = 1.f / ls1;
        ctx0[d0] = cA0 * inv0; ctx0[d0 + 1] = cA1 * inv0;
        ctx1[d0] = cB0 * inv1; ctx1[d0 + 1] = cB1 * inv1;
        for (int idx = tid; idx < 392; idx += 256) {
            const int l = idx & 1, p = idx >> 1;
            const float sc = sraw[l * 208 + p];
            out_attn[((size_t)b * 32 + l0 + l) * 196 + p] =
                __expf(sc - (l ? m1 : m0)) * (l ? inv1 : inv0);
        }
    }
    __syncthreads();

    // ---- Phase 3: out rows = (ctx . W_co^T + b_co) * hiddens rows ----
    {
        float4 xA[8], xB[8];
        #pragma unroll
        for (int j = 0; j < 8; ++j) {
            xA[j] = *(const float4*)&ctx0[koff[j]];
            xB[j] = *(const float4*)&ctx1[koff[j]];
        }
        float* o0 = out_co + ((size_t)b * 32 + l0) * 512;
        float* o1 = o0 + 512;
        for (int it = 0; it < 32; ++it) {
            const int h = it * 16 + aslot;
            const float* wrow = W_co + (size_t)h * 512;
            float a0 = 0.f, a1 = 0.f;
            #pragma unroll
            for (int j = 0; j < 8; ++j) {
                const float4 w = *(const float4*)(wrow + koff[j]);
                a0 += w.x*xA[j].x + w.y*xA[j].y + w.z*xA[j].z + w.w*xA[j].w;
                a1 += w.x*xB[j].x + w.y*xB[j].y + w.z*xB[j].z + w.w*xB[j].w;
            }
            #pragma unroll
            for (int msk = 1; msk <= 8; msk <<= 1) {
                a0 += __shfl_xor(a0, msk);
                a1 += __shfl_xor(a1, msk);
            }
            if (kc == 0) {
                const float bo = b_co[h];
                o0[h] = (a0 + bo) * hid0[h];
                o1[h] = (a1 + bo) * hid1[h];
            }
        }
    }
}

extern "C" void kernel_launch(void* const* d_in, const int* in_sizes, int n_in,
                              void* d_out, int out_size, void* d_ws, size_t ws_size,
                              hipStream_t stream)
{
    const float* maps     = (const float*)d_in[0];
    const float* hiddens  = (const float*)d_in[1];
    const float* W_hidden = (const float*)d_in[2];
    const float* b_hidden = (const float*)d_in[3];
    const float* W_rect   = (const float*)d_in[4];
    const float* b_rect   = (const float*)d_in[5];
    const float* W_co     = (const float*)d_in[6];
    const float* b_co     = (const float*)d_in[7];

    float* out_co   = (float*)d_out;                    // (512,512)
    float* out_attn = out_co + (size_t)512 * 512;       // (512,196)

    hipLaunchKernelGGL(coatt_onekernel, dim3(256), dim3(256), 0, stream,
                       maps, hiddens, W_hidden, b_hidden, W_rect, b_rect,
                       W_co, b_co, out_co, out_attn);
}